// Round 12
// baseline (161.649 us; speedup 1.0000x reference)
//
#include <hip/hip_runtime.h>
#include <math.h>

// EfficientAttention, fp16-MFMA, register-dataflow version.
//   ctx_h = softmax_N(k_h) @ v_h^T folded with Wr into M[n][oc][p] (p=h*16+kc):
//   out = M @ softmax_dk(q) + br.
// R12: k_ctx latency-hiding via TLP -- 4096 blocks x 128 tokens (2 subtiles
// per wave, both loads issued up front), S/Z atomics into 16 contention
// slices reduced by k_m. k_out unchanged (~94% of memory floor).

#define NTOK 262144
typedef float4 f4;
typedef _Float16 f16;
typedef __attribute__((ext_vector_type(8))) _Float16 f16x8;
typedef __attribute__((ext_vector_type(4))) _Float16 f16x4;
typedef __attribute__((ext_vector_type(4))) float f32x4;

// ---- workspace float offsets ----
#define WS_MH 2176    // 4096 float slots = 8192 f16 : M[n][c][p]  (2176..6272)
#define WS_SP 6272    // 32768 : S partials [16 slices][n][h][kc][vc] f32
#define WS_ZP 39040   // 2048  : Z partials [16 slices][n][h*16+kc] f32
// zero range for k_init: [WS_SP, WS_SP + 34816)

__device__ __forceinline__ f16x8 cvt8h2(f4 a, f4 b) {
    f16x8 r;
    r[0] = (f16)a.x; r[1] = (f16)a.y; r[2] = (f16)a.z; r[3] = (f16)a.w;
    r[4] = (f16)b.x; r[5] = (f16)b.y; r[6] = (f16)b.z; r[7] = (f16)b.w;
    return r;
}

__global__ __launch_bounds__(256) void k_init(float* __restrict__ ws) {
    int i = blockIdx.x * 256 + threadIdx.x;   // grid 136 -> 34816 threads
    if (i < 34816) ws[WS_SP + i] = 0.0f;      // zero S/Z slices
}

// ---------------- Pass 1: k,v projection + ctx accumulation ----------------
// Block = 128 tokens, wave w owns [w*32, w*32+32): 2 subtiles of 16, all 4
// heads. Both subtile loads issued up front; latency hidden by 8 blocks/CU.
// Proj: A = x rows (token=lr, j=8ql+m+32jc), B = Wk/Wv rows (c=16h+lr) ->
// D[t][c]: lane holds c=lr, t=4ql+r. Acc: S_h += EK_h^T x EV_h via
// mfma_16x16x16f16 with ekf/evf = f16 of the D registers directly.
__global__ __launch_bounds__(256) void k_ctx(const float* __restrict__ x,
                                             const float* __restrict__ Wk,
                                             const float* __restrict__ Wv,
                                             float* __restrict__ ws) {
    __shared__ float sr[4096];   // epilogue: [w][h][kc][vc]
    __shared__ float zr[256];    // epilogue: [w][h][kc]

    const int tid  = threadIdx.x;
    const int w    = tid >> 6;
    const int lane = tid & 63;
    const int lr   = lane & 15;
    const int ql   = lane >> 4;

    const int nb = blockIdx.x >> 11;
    const int bi = blockIdx.x & 2047;
    const int sl = bi & 15;                  // contention slice
    const long base = (long)nb * NTOK + (long)bi * 128 + (long)w * 32;

    // issue both subtile loads up front (8 dwordx4 in flight)
    f4 A0, A1, A2, A3, B0, B1, B2, B3;
    {
        const float* xp = x + (((size_t)(base + lr)) << 6) + 8 * ql;
        A0 = *(const f4*)xp;        A1 = *(const f4*)(xp + 4);
        A2 = *(const f4*)(xp + 32); A3 = *(const f4*)(xp + 36);
        const float* yp = x + (((size_t)(base + 16 + lr)) << 6) + 8 * ql;
        B0 = *(const f4*)yp;        B1 = *(const f4*)(yp + 4);
        B2 = *(const f4*)(yp + 32); B3 = *(const f4*)(yp + 36);
    }

    // B-frags for all heads (f16, register-resident): lane c=16h+lr, k=32jc+8ql+m
    f16x8 wkf[4][2], wvf[4][2];
    #pragma unroll
    for (int h = 0; h < 4; ++h) {
        const float* kr = &Wk[(16 * h + lr) * 64 + 8 * ql];
        const float* vr = &Wv[(16 * h + lr) * 64 + 8 * ql];
        #pragma unroll
        for (int jc = 0; jc < 2; ++jc) {
            wkf[h][jc] = cvt8h2(*(const f4*)&kr[32 * jc], *(const f4*)&kr[32 * jc + 4]);
            wvf[h][jc] = cvt8h2(*(const f4*)&vr[32 * jc], *(const f4*)&vr[32 * jc + 4]);
        }
    }

    const f32x4 zero4 = {0.f, 0.f, 0.f, 0.f};
    f32x4 S[4] = {zero4, zero4, zero4, zero4};
    float z[4] = {0.f, 0.f, 0.f, 0.f};

    // subtile A
    {
        f16x8 a0 = cvt8h2(A0, A1), a1 = cvt8h2(A2, A3);
        #pragma unroll
        for (int h = 0; h < 4; ++h) {
            f32x4 ak = zero4, av = zero4;
            ak = __builtin_amdgcn_mfma_f32_16x16x32_f16(a0, wkf[h][0], ak, 0, 0, 0);
            ak = __builtin_amdgcn_mfma_f32_16x16x32_f16(a1, wkf[h][1], ak, 0, 0, 0);
            av = __builtin_amdgcn_mfma_f32_16x16x32_f16(a0, wvf[h][0], av, 0, 0, 0);
            av = __builtin_amdgcn_mfma_f32_16x16x32_f16(a1, wvf[h][1], av, 0, 0, 0);
            // no bk: softmax over spatial axis is invariant to per-channel shift
            const float e0 = __expf(ak[0]), e1 = __expf(ak[1]);
            const float e2 = __expf(ak[2]), e3 = __expf(ak[3]);
            z[h] += (e0 + e1) + (e2 + e3);
            f16x4 ekf = {(f16)e0, (f16)e1, (f16)e2, (f16)e3};
            f16x4 evf = {(f16)av[0], (f16)av[1], (f16)av[2], (f16)av[3]};
            S[h] = __builtin_amdgcn_mfma_f32_16x16x16f16(ekf, evf, S[h], 0, 0, 0);
        }
    }
    // subtile B
    {
        f16x8 a0 = cvt8h2(B0, B1), a1 = cvt8h2(B2, B3);
        #pragma unroll
        for (int h = 0; h < 4; ++h) {
            f32x4 ak = zero4, av = zero4;
            ak = __builtin_amdgcn_mfma_f32_16x16x32_f16(a0, wkf[h][0], ak, 0, 0, 0);
            ak = __builtin_amdgcn_mfma_f32_16x16x32_f16(a1, wkf[h][1], ak, 0, 0, 0);
            av = __builtin_amdgcn_mfma_f32_16x16x32_f16(a0, wvf[h][0], av, 0, 0, 0);
            av = __builtin_amdgcn_mfma_f32_16x16x32_f16(a1, wvf[h][1], av, 0, 0, 0);
            const float e0 = __expf(ak[0]), e1 = __expf(ak[1]);
            const float e2 = __expf(ak[2]), e3 = __expf(ak[3]);
            z[h] += (e0 + e1) + (e2 + e3);
            f16x4 ekf = {(f16)e0, (f16)e1, (f16)e2, (f16)e3};
            f16x4 evf = {(f16)av[0], (f16)av[1], (f16)av[2], (f16)av[3]};
            S[h] = __builtin_amdgcn_mfma_f32_16x16x16f16(ekf, evf, S[h], 0, 0, 0);
        }
    }

    // z: quartile lanes (lr, lr+16, lr+32, lr+48) hold same kc=lr
    #pragma unroll
    for (int h = 0; h < 4; ++h) {
        z[h] += __shfl_xor(z[h], 16);
        z[h] += __shfl_xor(z[h], 32);
    }

    // block-level reduction of S,z in LDS, then sliced atomics.
    // S D-layout: col vc=lr, row kc=4ql+r.
    #pragma unroll
    for (int h = 0; h < 4; ++h) {
        #pragma unroll
        for (int r = 0; r < 4; ++r)
            sr[((w * 4 + h) * 16 + 4 * ql + r) * 16 + lr] = S[h][r];
        if (lane < 16) zr[(w * 4 + h) * 16 + lane] = z[h];
    }
    __syncthreads();
    const int sbase = WS_SP + (sl * 2 + nb) * 1024;
    #pragma unroll
    for (int i = 0; i < 4; ++i) {
        const int idx = i * 256 + tid;     // h=i, kc=tid>>4, vc=tid&15
        const float acc = sr[idx] + sr[1024 + idx] + sr[2048 + idx] + sr[3072 + idx];
        atomicAdd(&ws[sbase + idx], acc);
    }
    if (tid < 64) {
        const float acc = zr[tid] + zr[64 + tid] + zr[128 + tid] + zr[192 + tid];
        atomicAdd(&ws[WS_ZP + (sl * 2 + nb) * 64 + tid], acc);
    }
}

// ---------- M = Wr @ (S/Z + bv) fold over slices : M[n][c][p] in fp16 ------
__global__ __launch_bounds__(256) void k_m(const float* __restrict__ Wr,
                                           const float* __restrict__ bv,
                                           float* __restrict__ ws) {
    const int n = blockIdx.x >> 4;
    const int i = (blockIdx.x & 15) * 256 + threadIdx.x;
    f16* MH = (f16*)(ws + WS_MH);
    const int c = i >> 6, p = i & 63;
    const int h = p >> 4, kc = p & 15;
    float zsum = 0.f;
    #pragma unroll
    for (int sl = 0; sl < 16; ++sl)
        zsum += ws[WS_ZP + (sl * 2 + n) * 64 + p];
    const float rz = 1.0f / zsum;
    const float* Wrow = Wr + c * 64 + h * 16;
    const float* bvr  = bv + h * 16;
    float acc = 0.f, accb = 0.f;
    #pragma unroll
    for (int vc = 0; vc < 16; ++vc) accb += Wrow[vc] * bvr[vc];
    for (int sl = 0; sl < 16; ++sl) {
        const float* Srow = ws + WS_SP + (sl * 2 + n) * 1024 + h * 256 + kc * 16;
        #pragma unroll
        for (int vc = 0; vc < 16; ++vc) acc += Wrow[vc] * Srow[vc];
    }
    MH[n * 4096 + c * 64 + p] = (f16)(acc * rz + accb);
}

// ---------------- Pass 2: q proj + softmax + M apply (fp16) ----------------
// Wave w owns tokens [w*64, w*64+64); all heads/oc-tiles; 4 subtiles of 16.
// Biases in f16 registers. No LDS, no barriers. (~94% of memory floor.)
__global__ __launch_bounds__(256) void k_out(const float* __restrict__ x,
                                             const float* __restrict__ Wq,
                                             const float* __restrict__ bq,
                                             const float* __restrict__ br,
                                             float* __restrict__ out,
                                             const float* __restrict__ ws) {
    const int tid  = threadIdx.x;
    const int w    = tid >> 6;
    const int lane = tid & 63;
    const int lr   = lane & 15;
    const int ql   = lane >> 4;

    const int nb = blockIdx.x >> 10;
    const int bi = blockIdx.x & 1023;
    const long base = (long)nb * NTOK + (long)bi * 256 + (long)w * 64;

    // Wq A-frags for all heads: lane row c(within head)=lr, k=32jc+8ql+m
    f16x8 wqf[4][2];
    f16x4 bqh[4];
    #pragma unroll
    for (int h = 0; h < 4; ++h) {
        const float* qr = &Wq[(16 * h + lr) * 64 + 8 * ql];
        #pragma unroll
        for (int jc = 0; jc < 2; ++jc)
            wqf[h][jc] = cvt8h2(*(const f4*)&qr[32 * jc], *(const f4*)&qr[32 * jc + 4]);
        const f4 b = *(const f4*)&bq[16 * h + 4 * ql];
        bqh[h][0] = (f16)b.x; bqh[h][1] = (f16)b.y;
        bqh[h][2] = (f16)b.z; bqh[h][3] = (f16)b.w;
    }
    // M A-frags for 16x16x16: [oct][pc], lane row oc=16oct+lr, k=p=16pc+4ql+m
    f16x4 mfa[4][4];
    f16x4 brh[4];
    const f16* MH = (const f16*)(ws + WS_MH) + (size_t)nb * 4096;
    #pragma unroll
    for (int oct = 0; oct < 4; ++oct) {
        #pragma unroll
        for (int pc = 0; pc < 4; ++pc)
            mfa[oct][pc] = *(const f16x4*)&MH[(16 * oct + lr) * 64 + 16 * pc + 4 * ql];
        const f4 b = *(const f4*)&br[16 * oct + 4 * ql];
        brh[oct][0] = (f16)b.x; brh[oct][1] = (f16)b.y;
        brh[oct][2] = (f16)b.z; brh[oct][3] = (f16)b.w;
    }

    const f32x4 zero4 = {0.f, 0.f, 0.f, 0.f};

    // depth-1 prefetch
    f4 L0, L1, L2, L3;
    {
        const float* xp = x + (((size_t)(base + lr)) << 6) + 8 * ql;
        L0 = *(const f4*)xp;        L1 = *(const f4*)(xp + 4);
        L2 = *(const f4*)(xp + 32); L3 = *(const f4*)(xp + 36);
    }

    for (int s = 0; s < 4; ++s) {
        f16x8 b0 = cvt8h2(L0, L1), b1 = cvt8h2(L2, L3);
        if (s < 3) {
            const float* xp = x + (((size_t)(base + (s + 1) * 16 + lr)) << 6) + 8 * ql;
            L0 = *(const f4*)xp;        L1 = *(const f4*)(xp + 4);
            L2 = *(const f4*)(xp + 32); L3 = *(const f4*)(xp + 36);
        }
        // phase A: q projection + per-head softmax over c; qf[h] = B-frag
        f16x4 qf[4];
        #pragma unroll
        for (int h = 0; h < 4; ++h) {
            f32x4 aq = zero4;
            aq = __builtin_amdgcn_mfma_f32_16x16x32_f16(wqf[h][0], b0, aq, 0, 0, 0);
            aq = __builtin_amdgcn_mfma_f32_16x16x32_f16(wqf[h][1], b1, aq, 0, 0, 0);
            float q0 = aq[0] + (float)bqh[h][0], q1 = aq[1] + (float)bqh[h][1];
            float q2 = aq[2] + (float)bqh[h][2], q3 = aq[3] + (float)bqh[h][3];
            float mx = fmaxf(fmaxf(q0, q1), fmaxf(q2, q3));
            mx = fmaxf(mx, __shfl_xor(mx, 16));
            mx = fmaxf(mx, __shfl_xor(mx, 32));
            float e0 = __expf(q0 - mx), e1 = __expf(q1 - mx);
            float e2 = __expf(q2 - mx), e3 = __expf(q3 - mx);
            float sm = (e0 + e1) + (e2 + e3);
            sm += __shfl_xor(sm, 16);
            sm += __shfl_xor(sm, 32);
            const float rs = 1.0f / sm;
            qf[h][0] = (f16)(e0 * rs); qf[h][1] = (f16)(e1 * rs);
            qf[h][2] = (f16)(e2 * rs); qf[h][3] = (f16)(e3 * rs);
        }
        // phase B: out = M x qhat + br, all in registers
        const size_t obase = ((size_t)(base + s * 16 + lr)) << 6;
        #pragma unroll
        for (int oct = 0; oct < 4; ++oct) {
            f32x4 o = zero4;
            #pragma unroll
            for (int pc = 0; pc < 4; ++pc)
                o = __builtin_amdgcn_mfma_f32_16x16x16f16(mfa[oct][pc], qf[pc], o, 0, 0, 0);
            const f4 res = {o[0] + (float)brh[oct][0], o[1] + (float)brh[oct][1],
                            o[2] + (float)brh[oct][2], o[3] + (float)brh[oct][3]};
            *(f4*)&out[obase + 16 * oct + 4 * ql] = res;
        }
    }
}

extern "C" void kernel_launch(void* const* d_in, const int* in_sizes, int n_in,
                              void* d_out, int out_size, void* d_ws, size_t ws_size,
                              hipStream_t stream) {
    const float* x  = (const float*)d_in[0];
    const float* Wk = (const float*)d_in[1];
    const float* Wq = (const float*)d_in[3];
    const float* bq = (const float*)d_in[4];
    const float* Wv = (const float*)d_in[5];
    const float* bv = (const float*)d_in[6];
    const float* Wr = (const float*)d_in[7];
    const float* br = (const float*)d_in[8];
    float* out = (float*)d_out;
    float* ws  = (float*)d_ws;

    hipLaunchKernelGGL(k_init, dim3(136),  dim3(256), 0, stream, ws);
    hipLaunchKernelGGL(k_ctx,  dim3(4096), dim3(256), 0, stream, x, Wk, Wv, ws);
    hipLaunchKernelGGL(k_m,    dim3(32),   dim3(256), 0, stream, Wr, bv, ws);
    hipLaunchKernelGGL(k_out,  dim3(2048), dim3(256), 0, stream, x, Wq, bq, br, out, ws);
}

// Round 13
// 151.806 us; speedup vs baseline: 1.0648x; 1.0648x over previous
//
#include <hip/hip_runtime.h>
#include <math.h>

// EfficientAttention, fp16-MFMA, register-dataflow version.
//   ctx_h = softmax_N(k_h) @ v_h^T folded with Wr into M[n][oc][p] (p=h*16+kc):
//   out = M @ softmax_dk(q) + br.
// R13: k_ctx atomics ELIMINATED -- each block stores its 1024+64 partial sums
// to a private slot (plain coalesced stores); k_red reduces slots -> S/Z.
// Geometry identical to R11 (1024 blocks x 512 tokens, wave owns 128 tokens).

#define NTOK 262144
typedef float4 f4;
typedef _Float16 f16;
typedef __attribute__((ext_vector_type(8))) _Float16 f16x8;
typedef __attribute__((ext_vector_type(4))) _Float16 f16x4;
typedef __attribute__((ext_vector_type(4))) float f32x4;

// ---- workspace float offsets ----
#define WS_S  0        // 2048 : S[n][h][kc][vc] f32 (reduced)
#define WS_Z  2048     // 128  : Z[n][h*16+kc]   f32 (reduced)
#define WS_MH 2176     // 4096 float slots = 8192 f16 : M[n][c][p]
#define WS_SP 6272     // 1024*1024 : S partials [block][idx]
#define WS_ZP 1054848  // 1024*64   : Z partials [block][zidx]

__device__ __forceinline__ f16x8 cvt8h2(f4 a, f4 b) {
    f16x8 r;
    r[0] = (f16)a.x; r[1] = (f16)a.y; r[2] = (f16)a.z; r[3] = (f16)a.w;
    r[4] = (f16)b.x; r[5] = (f16)b.y; r[6] = (f16)b.z; r[7] = (f16)b.w;
    return r;
}

// ---------------- Pass 1: k,v projection + ctx accumulation ----------------
// Block = 512 tokens, wave w owns [w*128, w*128+128): 8 subtiles of 16,
// all 4 heads, depth-2 prefetch.
// Proj: A = x rows (token=lr, j=8ql+m+32jc), B = Wk/Wv rows (c=16h+lr) ->
// D[t][c]: lane holds c=lr, t=4ql+r. Acc: S_h += EK_h^T x EV_h via
// mfma_16x16x16f16 with ekf/evf = f16 of the D registers directly.
// Epilogue: LDS reduce across waves -> PRIVATE partial slot (no atomics).
__global__ __launch_bounds__(256) void k_ctx(const float* __restrict__ x,
                                             const float* __restrict__ Wk,
                                             const float* __restrict__ Wv,
                                             float* __restrict__ ws) {
    __shared__ float sr[4096];   // epilogue: [w][idx], idx = h*256+kc*16+vc
    __shared__ float zr[256];    // epilogue: [w][h*16+kc]

    const int tid  = threadIdx.x;
    const int w    = tid >> 6;
    const int lane = tid & 63;
    const int lr   = lane & 15;
    const int ql   = lane >> 4;

    const int nb = blockIdx.x >> 9;
    const int bi = blockIdx.x & 511;
    const long base = (long)nb * NTOK + (long)bi * 512 + (long)w * 128;

    // B-frags for all heads (f16, register-resident): lane c=16h+lr, k=32jc+8ql+m
    f16x8 wkf[4][2], wvf[4][2];
    #pragma unroll
    for (int h = 0; h < 4; ++h) {
        const float* kr = &Wk[(16 * h + lr) * 64 + 8 * ql];
        const float* vr = &Wv[(16 * h + lr) * 64 + 8 * ql];
        #pragma unroll
        for (int jc = 0; jc < 2; ++jc) {
            wkf[h][jc] = cvt8h2(*(const f4*)&kr[32 * jc], *(const f4*)&kr[32 * jc + 4]);
            wvf[h][jc] = cvt8h2(*(const f4*)&vr[32 * jc], *(const f4*)&vr[32 * jc + 4]);
        }
    }

    const f32x4 zero4 = {0.f, 0.f, 0.f, 0.f};
    f32x4 S[4] = {zero4, zero4, zero4, zero4};
    float z[4] = {0.f, 0.f, 0.f, 0.f};

    // depth-2 prefetch: buffer A = even subtile, buffer B = odd subtile
    f4 A0, A1, A2, A3, B0, B1, B2, B3;
    {
        const float* xp = x + (((size_t)(base + lr)) << 6) + 8 * ql;
        A0 = *(const f4*)xp;        A1 = *(const f4*)(xp + 4);
        A2 = *(const f4*)(xp + 32); A3 = *(const f4*)(xp + 36);
        const float* yp = x + (((size_t)(base + 16 + lr)) << 6) + 8 * ql;
        B0 = *(const f4*)yp;        B1 = *(const f4*)(yp + 4);
        B2 = *(const f4*)(yp + 32); B3 = *(const f4*)(yp + 36);
    }

    for (int s = 0; s < 4; ++s) {   // processes subtiles 2s (A) and 2s+1 (B)
        {
            f16x8 a0 = cvt8h2(A0, A1), a1 = cvt8h2(A2, A3);
            if (s < 3) {
                const float* xp = x + (((size_t)(base + (2 * s + 2) * 16 + lr)) << 6) + 8 * ql;
                A0 = *(const f4*)xp;        A1 = *(const f4*)(xp + 4);
                A2 = *(const f4*)(xp + 32); A3 = *(const f4*)(xp + 36);
            }
            #pragma unroll
            for (int h = 0; h < 4; ++h) {
                f32x4 ak = zero4, av = zero4;
                ak = __builtin_amdgcn_mfma_f32_16x16x32_f16(a0, wkf[h][0], ak, 0, 0, 0);
                ak = __builtin_amdgcn_mfma_f32_16x16x32_f16(a1, wkf[h][1], ak, 0, 0, 0);
                av = __builtin_amdgcn_mfma_f32_16x16x32_f16(a0, wvf[h][0], av, 0, 0, 0);
                av = __builtin_amdgcn_mfma_f32_16x16x32_f16(a1, wvf[h][1], av, 0, 0, 0);
                const float e0 = __expf(ak[0]), e1 = __expf(ak[1]);
                const float e2 = __expf(ak[2]), e3 = __expf(ak[3]);
                z[h] += (e0 + e1) + (e2 + e3);
                f16x4 ekf = {(f16)e0, (f16)e1, (f16)e2, (f16)e3};
                f16x4 evf = {(f16)av[0], (f16)av[1], (f16)av[2], (f16)av[3]};
                S[h] = __builtin_amdgcn_mfma_f32_16x16x16f16(ekf, evf, S[h], 0, 0, 0);
            }
        }
        {
            f16x8 a0 = cvt8h2(B0, B1), a1 = cvt8h2(B2, B3);
            if (s < 3) {
                const float* xp = x + (((size_t)(base + (2 * s + 3) * 16 + lr)) << 6) + 8 * ql;
                B0 = *(const f4*)xp;        B1 = *(const f4*)(xp + 4);
                B2 = *(const f4*)(xp + 32); B3 = *(const f4*)(xp + 36);
            }
            #pragma unroll
            for (int h = 0; h < 4; ++h) {
                f32x4 ak = zero4, av = zero4;
                ak = __builtin_amdgcn_mfma_f32_16x16x32_f16(a0, wkf[h][0], ak, 0, 0, 0);
                ak = __builtin_amdgcn_mfma_f32_16x16x32_f16(a1, wkf[h][1], ak, 0, 0, 0);
                av = __builtin_amdgcn_mfma_f32_16x16x32_f16(a0, wvf[h][0], av, 0, 0, 0);
                av = __builtin_amdgcn_mfma_f32_16x16x32_f16(a1, wvf[h][1], av, 0, 0, 0);
                const float e0 = __expf(ak[0]), e1 = __expf(ak[1]);
                const float e2 = __expf(ak[2]), e3 = __expf(ak[3]);
                z[h] += (e0 + e1) + (e2 + e3);
                f16x4 ekf = {(f16)e0, (f16)e1, (f16)e2, (f16)e3};
                f16x4 evf = {(f16)av[0], (f16)av[1], (f16)av[2], (f16)av[3]};
                S[h] = __builtin_amdgcn_mfma_f32_16x16x16f16(ekf, evf, S[h], 0, 0, 0);
            }
        }
    }

    // z: quartile lanes (lr, lr+16, lr+32, lr+48) hold same kc=lr
    #pragma unroll
    for (int h = 0; h < 4; ++h) {
        z[h] += __shfl_xor(z[h], 16);
        z[h] += __shfl_xor(z[h], 32);
    }

    // block-level reduction in LDS -> private partial slot (plain stores).
    // S D-layout: col vc=lr, row kc=4ql+r.
    #pragma unroll
    for (int h = 0; h < 4; ++h) {
        #pragma unroll
        for (int r = 0; r < 4; ++r)
            sr[w * 1024 + h * 256 + (4 * ql + r) * 16 + lr] = S[h][r];
        if (lane < 16) zr[w * 64 + h * 16 + lane] = z[h];
    }
    __syncthreads();
    {
        const f4 v0 = *(const f4*)&sr[tid * 4];
        const f4 v1 = *(const f4*)&sr[1024 + tid * 4];
        const f4 v2 = *(const f4*)&sr[2048 + tid * 4];
        const f4 v3 = *(const f4*)&sr[3072 + tid * 4];
        const f4 acc = {v0.x + v1.x + v2.x + v3.x, v0.y + v1.y + v2.y + v3.y,
                        v0.z + v1.z + v2.z + v3.z, v0.w + v1.w + v2.w + v3.w};
        *(f4*)&ws[WS_SP + (size_t)blockIdx.x * 1024 + tid * 4] = acc;
    }
    if (tid < 64) {
        const float acc = zr[tid] + zr[64 + tid] + zr[128 + tid] + zr[192 + tid];
        ws[WS_ZP + (size_t)blockIdx.x * 64 + tid] = acc;
    }
}

// ---------- reduce private partials -> S[n][1024], Z[n][64] ----------
// Coalesced: a wave reads 64 consecutive floats of each partial slot.
__global__ __launch_bounds__(256) void k_red(float* __restrict__ ws) {
    const int i = blockIdx.x * 256 + threadIdx.x;   // grid 9 -> 2304 threads
    if (i < 2048) {
        const int n = i >> 10, idx = i & 1023;
        float s = 0.f;
        for (int b = 0; b < 512; ++b)
            s += ws[WS_SP + (size_t)((n << 9) + b) * 1024 + idx];
        ws[WS_S + n * 1024 + idx] = s;
    } else if (i < 2176) {
        const int j = i - 2048;
        const int n = j >> 6, idx = j & 63;
        float s = 0.f;
        for (int b = 0; b < 512; ++b)
            s += ws[WS_ZP + (size_t)((n << 9) + b) * 64 + idx];
        ws[WS_Z + n * 64 + idx] = s;
    }
}

// ---------- M = Wr @ (S/Z + bv) fold : M[n][c][p] in fp16 ----------
__global__ __launch_bounds__(256) void k_m(const float* __restrict__ Wr,
                                           const float* __restrict__ bv,
                                           float* __restrict__ ws) {
    const int n = blockIdx.x >> 4;
    const int i = (blockIdx.x & 15) * 256 + threadIdx.x;
    f16* MH = (f16*)(ws + WS_MH);
    const int c = i >> 6, p = i & 63;
    const int h = p >> 4, kc = p & 15;
    const float rz = 1.0f / ws[WS_Z + n * 64 + p];
    const float* Srow = ws + WS_S + n * 1024 + h * 256 + kc * 16;
    const float* Wrow = Wr + c * 64 + h * 16;
    const float* bvr  = bv + h * 16;
    float acc = 0.f, accb = 0.f;
    #pragma unroll
    for (int vc = 0; vc < 16; ++vc) {
        acc  += Wrow[vc] * Srow[vc];
        accb += Wrow[vc] * bvr[vc];
    }
    MH[n * 4096 + c * 64 + p] = (f16)(acc * rz + accb);
}

// ---------------- Pass 2: q proj + softmax + M apply (fp16) ----------------
// Wave w owns tokens [w*64, w*64+64); all heads/oc-tiles; 4 subtiles of 16.
// Biases in f16 registers. No LDS, no barriers. (~94% of memory floor.)
__global__ __launch_bounds__(256) void k_out(const float* __restrict__ x,
                                             const float* __restrict__ Wq,
                                             const float* __restrict__ bq,
                                             const float* __restrict__ br,
                                             float* __restrict__ out,
                                             const float* __restrict__ ws) {
    const int tid  = threadIdx.x;
    const int w    = tid >> 6;
    const int lane = tid & 63;
    const int lr   = lane & 15;
    const int ql   = lane >> 4;

    const int nb = blockIdx.x >> 10;
    const int bi = blockIdx.x & 1023;
    const long base = (long)nb * NTOK + (long)bi * 256 + (long)w * 64;

    // Wq A-frags for all heads: lane row c(within head)=lr, k=32jc+8ql+m
    f16x8 wqf[4][2];
    f16x4 bqh[4];
    #pragma unroll
    for (int h = 0; h < 4; ++h) {
        const float* qr = &Wq[(16 * h + lr) * 64 + 8 * ql];
        #pragma unroll
        for (int jc = 0; jc < 2; ++jc)
            wqf[h][jc] = cvt8h2(*(const f4*)&qr[32 * jc], *(const f4*)&qr[32 * jc + 4]);
        const f4 b = *(const f4*)&bq[16 * h + 4 * ql];
        bqh[h][0] = (f16)b.x; bqh[h][1] = (f16)b.y;
        bqh[h][2] = (f16)b.z; bqh[h][3] = (f16)b.w;
    }
    // M A-frags for 16x16x16: [oct][pc], lane row oc=16oct+lr, k=p=16pc+4ql+m
    f16x4 mfa[4][4];
    f16x4 brh[4];
    const f16* MH = (const f16*)(ws + WS_MH) + (size_t)nb * 4096;
    #pragma unroll
    for (int oct = 0; oct < 4; ++oct) {
        #pragma unroll
        for (int pc = 0; pc < 4; ++pc)
            mfa[oct][pc] = *(const f16x4*)&MH[(16 * oct + lr) * 64 + 16 * pc + 4 * ql];
        const f4 b = *(const f4*)&br[16 * oct + 4 * ql];
        brh[oct][0] = (f16)b.x; brh[oct][1] = (f16)b.y;
        brh[oct][2] = (f16)b.z; brh[oct][3] = (f16)b.w;
    }

    const f32x4 zero4 = {0.f, 0.f, 0.f, 0.f};

    // depth-1 prefetch
    f4 L0, L1, L2, L3;
    {
        const float* xp = x + (((size_t)(base + lr)) << 6) + 8 * ql;
        L0 = *(const f4*)xp;        L1 = *(const f4*)(xp + 4);
        L2 = *(const f4*)(xp + 32); L3 = *(const f4*)(xp + 36);
    }

    for (int s = 0; s < 4; ++s) {
        f16x8 b0 = cvt8h2(L0, L1), b1 = cvt8h2(L2, L3);
        if (s < 3) {
            const float* xp = x + (((size_t)(base + (s + 1) * 16 + lr)) << 6) + 8 * ql;
            L0 = *(const f4*)xp;        L1 = *(const f4*)(xp + 4);
            L2 = *(const f4*)(xp + 32); L3 = *(const f4*)(xp + 36);
        }
        // phase A: q projection + per-head softmax over c; qf[h] = B-frag
        f16x4 qf[4];
        #pragma unroll
        for (int h = 0; h < 4; ++h) {
            f32x4 aq = zero4;
            aq = __builtin_amdgcn_mfma_f32_16x16x32_f16(wqf[h][0], b0, aq, 0, 0, 0);
            aq = __builtin_amdgcn_mfma_f32_16x16x32_f16(wqf[h][1], b1, aq, 0, 0, 0);
            float q0 = aq[0] + (float)bqh[h][0], q1 = aq[1] + (float)bqh[h][1];
            float q2 = aq[2] + (float)bqh[h][2], q3 = aq[3] + (float)bqh[h][3];
            float mx = fmaxf(fmaxf(q0, q1), fmaxf(q2, q3));
            mx = fmaxf(mx, __shfl_xor(mx, 16));
            mx = fmaxf(mx, __shfl_xor(mx, 32));
            float e0 = __expf(q0 - mx), e1 = __expf(q1 - mx);
            float e2 = __expf(q2 - mx), e3 = __expf(q3 - mx);
            float sm = (e0 + e1) + (e2 + e3);
            sm += __shfl_xor(sm, 16);
            sm += __shfl_xor(sm, 32);
            const float rs = 1.0f / sm;
            qf[h][0] = (f16)(e0 * rs); qf[h][1] = (f16)(e1 * rs);
            qf[h][2] = (f16)(e2 * rs); qf[h][3] = (f16)(e3 * rs);
        }
        // phase B: out = M x qhat + br, all in registers
        const size_t obase = ((size_t)(base + s * 16 + lr)) << 6;
        #pragma unroll
        for (int oct = 0; oct < 4; ++oct) {
            f32x4 o = zero4;
            #pragma unroll
            for (int pc = 0; pc < 4; ++pc)
                o = __builtin_amdgcn_mfma_f32_16x16x16f16(mfa[oct][pc], qf[pc], o, 0, 0, 0);
            const f4 res = {o[0] + (float)brh[oct][0], o[1] + (float)brh[oct][1],
                            o[2] + (float)brh[oct][2], o[3] + (float)brh[oct][3]};
            *(f4*)&out[obase + 16 * oct + 4 * ql] = res;
        }
    }
}

extern "C" void kernel_launch(void* const* d_in, const int* in_sizes, int n_in,
                              void* d_out, int out_size, void* d_ws, size_t ws_size,
                              hipStream_t stream) {
    const float* x  = (const float*)d_in[0];
    const float* Wk = (const float*)d_in[1];
    const float* Wq = (const float*)d_in[3];
    const float* bq = (const float*)d_in[4];
    const float* Wv = (const float*)d_in[5];
    const float* bv = (const float*)d_in[6];
    const float* Wr = (const float*)d_in[7];
    const float* br = (const float*)d_in[8];
    float* out = (float*)d_out;
    float* ws  = (float*)d_ws;

    hipLaunchKernelGGL(k_ctx,  dim3(1024), dim3(256), 0, stream, x, Wk, Wv, ws);
    hipLaunchKernelGGL(k_red,  dim3(9),    dim3(256), 0, stream, ws);
    hipLaunchKernelGGL(k_m,    dim3(32),   dim3(256), 0, stream, Wr, bv, ws);
    hipLaunchKernelGGL(k_out,  dim3(2048), dim3(256), 0, stream, x, Wq, bq, br, out, ws);
}